// Round 1
// 3373.775 us; speedup vs baseline: 1.3590x; 1.3590x over previous
//
#include <hip/hip_runtime.h>
#include <hip/hip_bf16.h>
#include <math.h>

// ---------------- problem constants ----------------
#define TT   128      // timesteps
#define BB   128      // batch
#define UU   512      // LSTM units
#define EMBD 300      // embedding dim
#define EMBP 320      // padded embedding dim (multiple of 32 for MFMA K)
#define NBLK 768      // 2 dir x 3 layers x 128 column-blocks (3 blocks/CU)
#define DBLK 384      // blocks per direction
#define NTHR 256

using bf16x8 = __attribute__((ext_vector_type(8))) short;
using f32x4  = __attribute__((ext_vector_type(4))) float;

// ws layout: flags 3KB | epoch @4096 | X 10MB | H 6 slots (write-once!) | hf
#define NEED_WS 111681536ull
static void* g_pool = nullptr;
__attribute__((constructor)) static void alloc_pool() {
    if (hipMalloc(&g_pool, 120ull * 1024ull * 1024ull) != hipSuccess) g_pool = nullptr;
}

__device__ __forceinline__ float b2f(unsigned short u) {
    union { unsigned int i; float f; } v; v.i = ((unsigned int)u) << 16; return v.f;
}
__device__ __forceinline__ unsigned short f2b(float f) {
    union { unsigned int i; float f; } v; v.f = f;
    unsigned int i = v.i;
    return (unsigned short)((i + 0x7fffu + ((i >> 16) & 1u)) >> 16);  // RNE
}
__device__ __forceinline__ unsigned short ld_bf(const void* p, size_t i, int f32) {
    return f32 ? f2b(((const float*)p)[i]) : ((const unsigned short*)p)[i];
}
__device__ __forceinline__ float ld_f(const void* p, size_t i, int f32) {
    return f32 ? ((const float*)p)[i] : b2f(((const unsigned short*)p)[i]);
}
__device__ __forceinline__ float clampz(float x) {
    return fminf(fmaxf(x, -60.0f), 60.0f);
}
__device__ __forceinline__ float sigm(float x)  { return 1.0f / (1.0f + __expf(-x)); }
__device__ __forceinline__ float ssign(float x) { return x / (1.0f + fabsf(x)); }

__device__ __forceinline__ int detect_f32(const void* emb) {
    const unsigned int* w = (const unsigned int*)emb;
    int cnt = 0;
    #pragma unroll
    for (int i = 0; i < 64; ++i) {
        unsigned int e = (w[i] >> 23) & 0xFFu;
        cnt += (e >= 96u && e <= 159u) ? 1 : 0;
    }
    return cnt >= 48;
}

struct P {
    const int* ids;
    const void* emb;
    const void* Wm[2][3];
    const void* Um[2][3];
    const void* bm[2][3];
    const void *d0W, *d0b;
    const void *bn_gamma, *bn_beta, *bn_mean, *bn_var;
    const void *alpha, *d1W, *d1b;
    unsigned short* X;      // [TT][BB][EMBP] bf16 (written once, fence-full barrier after)
    unsigned short* H;      // [3 slots][2 dirs][TT][BB][UU] bf16 — WRITE-ONCE, write-through
    float* hf;              // [2][BB][UU] fp32 — write-through
    unsigned int* flags;    // [NBLK] per-block generation flags
    unsigned int* epoch;    // epoch[0]=dir0, epoch[64]=dir1 (separate lines)
    float* out;             // [BB][7] fp32
};

#define EPOFF 64   // dir1 epoch word offset (256 B from dir0)

__device__ __forceinline__ unsigned int ald(const unsigned int* a) {
    return __hip_atomic_load(a, __ATOMIC_RELAXED, __HIP_MEMORY_SCOPE_AGENT);
}
__device__ __forceinline__ void ast(unsigned int* a, unsigned int v) {
    __hip_atomic_store(a, v, __ATOMIC_RELAXED, __HIP_MEMORY_SCOPE_AGENT);
}

// fence-FULL flat barrier (phase 0 only; X uses normal cached stores)
__device__ __forceinline__ void gsync_fence(unsigned int* flags, unsigned int gen) {
    __syncthreads();
    if (threadIdx.x == 0) {
        __threadfence();
        ast(&flags[blockIdx.x], gen);
    }
    if (threadIdx.x < 64) {
        const int i = threadIdx.x;
        for (;;) {
            bool ok = true;
            #pragma unroll
            for (int j = 0; j < NBLK / 64; ++j)
                ok = ok && (ald(&flags[i + j * 64]) >= gen);
            if (__all(ok)) break;
            __builtin_amdgcn_s_sleep(1);
        }
        __threadfence();
    }
    __syncthreads();
}

// Two-level aggregated per-direction barrier (fence-free; data is
// write-through + write-once). Leaves store own flag; the direction's
// aggregator block polls its 384 flags and publishes one epoch word;
// everyone polls that single word (same-address broadcast load).
__device__ __forceinline__ void gsync_dir(P& p, int dirbase, int eidx, int isagg, unsigned int gen) {
    __syncthreads();
    if (threadIdx.x == 0)
        ast(&p.flags[blockIdx.x], gen);
    if (isagg && threadIdx.x < 64) {
        const unsigned int* f = p.flags + dirbase + threadIdx.x;
        for (;;) {
            bool ok = true;
            #pragma unroll
            for (int j = 0; j < DBLK / 64; ++j)
                ok = ok && (ald(f + j * 64) >= gen);
            if (__all(ok)) break;
            __builtin_amdgcn_s_sleep(1);
        }
        if (threadIdx.x == 0)
            ast(&p.epoch[eidx], gen);
    }
    if (threadIdx.x < 64) {
        const unsigned int* e = &p.epoch[eidx];
        while (ald(e) < gen) __builtin_amdgcn_s_sleep(1);
    }
    __syncthreads();
}

// full-grid aggregated barrier (before head)
__device__ __forceinline__ void gsync_all(P& p, int dirbase, int eidx, int isagg, unsigned int gen) {
    __syncthreads();
    if (threadIdx.x == 0)
        ast(&p.flags[blockIdx.x], gen);
    if (isagg && threadIdx.x < 64) {
        const unsigned int* f = p.flags + dirbase + threadIdx.x;
        for (;;) {
            bool ok = true;
            #pragma unroll
            for (int j = 0; j < DBLK / 64; ++j)
                ok = ok && (ald(f + j * 64) >= gen);
            if (__all(ok)) break;
            __builtin_amdgcn_s_sleep(1);
        }
        if (threadIdx.x == 0)
            ast(&p.epoch[eidx], gen);
    }
    if (threadIdx.x < 64) {
        while (!((ald(&p.epoch[0]) >= gen) && (ald(&p.epoch[EPOFF]) >= gen)))
            __builtin_amdgcn_s_sleep(1);
    }
    __syncthreads();
}

// one timestep's z = [A1 | A2] @ B panel for this wave's two 16-row tiles.
// K1T is a compile-time constant so the loops unroll and loads issue early.
template<int K1T>
__device__ __forceinline__ void mfma_step(
    const unsigned short* __restrict__ A1,     // stride K1T
    const unsigned short* __restrict__ A2,     // stride UU, nullptr at t==0
    const unsigned short (&Bt)[16][1032],
    int r0, int r1, int l15, int ko,
    f32x4& a0, f32x4& a1)
{
    {
        const unsigned short* ap0 = A1 + (size_t)r0 * K1T + ko;
        const unsigned short* ap1 = A1 + (size_t)r1 * K1T + ko;
        const unsigned short* bp  = &Bt[l15][ko];
        #pragma unroll 4
        for (int kt = 0; kt < K1T; kt += 32) {
            bf16x8 bv = *(const bf16x8*)(bp + kt);
            a0 = __builtin_amdgcn_mfma_f32_16x16x32_bf16(*(const bf16x8*)(ap0 + kt), bv, a0, 0, 0, 0);
            a1 = __builtin_amdgcn_mfma_f32_16x16x32_bf16(*(const bf16x8*)(ap1 + kt), bv, a1, 0, 0, 0);
        }
    }
    if (A2) {
        const unsigned short* ap0 = A2 + (size_t)r0 * UU + ko;
        const unsigned short* ap1 = A2 + (size_t)r1 * UU + ko;
        const unsigned short* bp  = &Bt[l15][K1T + ko];
        #pragma unroll 4
        for (int kt = 0; kt < UU; kt += 32) {
            bf16x8 bv = *(const bf16x8*)(bp + kt);
            a0 = __builtin_amdgcn_mfma_f32_16x16x32_bf16(*(const bf16x8*)(ap0 + kt), bv, a0, 0, 0, 0);
            a1 = __builtin_amdgcn_mfma_f32_16x16x32_bf16(*(const bf16x8*)(ap1 + kt), bv, a1, 0, 0, 0);
        }
    }
}

__global__ __launch_bounds__(NTHR, 3) void bilstm_persistent(P p) {
    const int blk = blockIdx.x;
    const int tid = threadIdx.x;

    const int f32 = detect_f32(p.emb);
    unsigned int gen = 0;

    __shared__ __align__(16) unsigned short Bt[16][1032];  // B panel [n][k] (33 KB)
    __shared__ __align__(16) float zld[128][17];           // z round-trip (8.7 KB)
    __shared__ float hact[256];
    __shared__ float lgts[8];

    // ---------------- phase 0: embedding gather (normal stores) ----------------
    for (int row = blk; row < TT * BB; row += NBLK) {
        int t = row >> 7, b = row & 127;
        int id = p.ids[b * TT + t];
        unsigned short* xr = p.X + (size_t)row * EMBP;
        for (int k2 = tid; k2 < EMBP; k2 += NTHR)
            xr[k2] = (k2 < EMBD) ? ld_bf(p.emb, (size_t)id * EMBD + k2, f32)
                                 : (unsigned short)0;
    }
    gsync_fence(p.flags, ++gen);             // only fence-full barrier in the kernel

    // block responsibilities: dir, layer (wavefront-pipelined), 4 h-columns, M=128
    const int dir     = (blk >= DBLK) ? 1 : 0;
    const int rb      = blk - dir * DBLK;
    const int layer   = rb >> 7;             // 0,1,2
    const int dirbase = dir * DBLK;
    const int eidx    = dir * EPOFF;
    const int isagg   = (rb == 0);
    const int j0      = (rb & 127) * 4;

    const int wv   = tid >> 6;               // wave 0..3
    const int lane = tid & 63;
    const int l15  = lane & 15;
    const int quad = lane >> 4;

    const int r_   = tid & 127;              // gate thread: row r_, 2 adjacent cols
    const int half = tid >> 7;               //   cols j0+2*half, j0+2*half+1
    const int jA   = 2 * half;

    const int r0   = wv * 32 + l15;
    const int r1   = r0 + 16;
    const int ko   = quad * 8;

    float cA = 0.0f, cB = 0.0f;              // cell state in registers

    const size_t seq = (size_t)TT * BB * UU;

    // ---- stage this block's B panel (16 gate-columns, its layer) into LDS ----
    const int KW   = (layer == 0) ? EMBD : UU;
    const int K1   = (layer == 0) ? EMBP : UU;
    const int Ktot = K1 + UU;
    const void* Wmat = p.Wm[dir][layer];
    const void* Umat = p.Um[dir][layer];
    const void* bias = p.bm[dir][layer];
    {
        int n = tid >> 4, ks = tid & 15;
        int wcol = (n >> 2) * UU + j0 + (n & 3);   // gate*512 + j
        for (int k2 = ks; k2 < Ktot; k2 += 16) {
            unsigned short v;
            if (k2 < KW)      v = ld_bf(Wmat, (size_t)k2 * 2048 + wcol, f32);
            else if (k2 < K1) v = 0;
            else              v = ld_bf(Umat, (size_t)(k2 - K1) * 2048 + wcol, f32);
            Bt[n][k2] = v;
        }
    }
    float bzA[4], bzB[4];
    #pragma unroll
    for (int g = 0; g < 4; ++g) {
        bzA[g] = ld_f(bias, g * UU + j0 + jA,     f32);
        bzB[g] = ld_f(bias, g * UU + j0 + jA + 1, f32);
    }
    __syncthreads();

    // write-once slots: layer l writes slot l, reads slot l-1
    unsigned short*       Hl  = p.H + (size_t)(layer * 2 + dir) * seq;
    const unsigned short* Hin = (layer > 0) ? (p.H + (size_t)((layer - 1) * 2 + dir) * seq) : nullptr;

    // ---------------- wavefront-pipelined step loop: 130 barriers/dir ----------------
    for (int s = 0; s < TT + 2; ++s) {
        const int t = s - layer;             // this layer's timestep at wavefront step s
        if (t >= 0 && t < TT) {
            const unsigned short* A2 = (t > 0) ? (Hl + (size_t)(t - 1) * BB * UU) : nullptr;

            f32x4 a0 = {0.f, 0.f, 0.f, 0.f};
            f32x4 a1 = {0.f, 0.f, 0.f, 0.f};

            if (layer == 0) {
                int tx = dir ? (TT - 1 - t) : t;
                const unsigned short* A1 = p.X + (size_t)tx * BB * EMBP;
                mfma_step<EMBP>(A1, A2, Bt, r0, r1, l15, ko, a0, a1);
            } else {
                const unsigned short* A1 = Hin + (size_t)t * BB * UU;
                mfma_step<UU>(A1, A2, Bt, r0, r1, l15, ko, a0, a1);
            }

            // D layout: col = lane&15, row = quad*4 + reg  (m89-verified)
            #pragma unroll
            for (int r = 0; r < 4; ++r) {
                zld[wv * 32 +      quad * 4 + r][l15] = a0[r];
                zld[wv * 32 + 16 + quad * 4 + r][l15] = a1[r];
            }
            __syncthreads();

            // ---- gates (fp32, clamped); one row x two cols per thread ----
            {
                float ziA = clampz(zld[r_][ 0 + jA] + bzA[0]);
                float zfA = clampz(zld[r_][ 4 + jA] + bzA[1]);
                float zgA = clampz(zld[r_][ 8 + jA] + bzA[2]);
                float zoA = clampz(zld[r_][12 + jA] + bzA[3]);
                float ziB = clampz(zld[r_][ 1 + jA] + bzB[0]);
                float zfB = clampz(zld[r_][ 5 + jA] + bzB[1]);
                float zgB = clampz(zld[r_][ 9 + jA] + bzB[2]);
                float zoB = clampz(zld[r_][13 + jA] + bzB[3]);
                float cpA = (t == 0) ? 0.0f : cA;
                float cpB = (t == 0) ? 0.0f : cB;
                float cnA = sigm(zfA) * cpA + sigm(ziA) * ssign(zgA);
                float cnB = sigm(zfB) * cpB + sigm(ziB) * ssign(zgB);
                cA = cnA; cB = cnB;
                float hA = sigm(zoA) * ssign(cnA);
                float hB = sigm(zoB) * ssign(cnB);
                // packed write-through store (device-coherent; never dirty in L2)
                unsigned int pk = (unsigned int)f2b(hA) | ((unsigned int)f2b(hB) << 16);
                __hip_atomic_store((unsigned int*)&Hl[(size_t)t * BB * UU + (size_t)r_ * UU + j0 + jA],
                                   pk, __ATOMIC_RELAXED, __HIP_MEMORY_SCOPE_AGENT);
                if (layer == 2 && t == TT - 1) {
                    size_t o = (size_t)dir * BB * UU + (size_t)r_ * UU + j0 + jA;
                    __hip_atomic_store(&p.hf[o],     hA, __ATOMIC_RELAXED, __HIP_MEMORY_SCOPE_AGENT);
                    __hip_atomic_store(&p.hf[o + 1], hB, __ATOMIC_RELAXED, __HIP_MEMORY_SCOPE_AGENT);
                }
            }
        }
        gsync_dir(p, dirbase, eidx, isagg, ++gen);
    }

    gsync_all(p, dirbase, eidx, isagg, ++gen);   // both dirs' hf complete before head

    // ---------------- head: block b handles batch row b (all fp32) ----------------
    if (blk < BB) {
        const int b = blk;
        const float* h0 = p.hf + (size_t)b * UU;
        const float* h1 = p.hf + (size_t)BB * UU + (size_t)b * UU;
        float acc = ld_f(p.d0b, tid, f32);
        #pragma unroll 8
        for (int k = 0; k < UU; ++k) {
            float a = 0.5f * (h0[k] + h1[k]);
            acc = fmaf(a, ld_f(p.d0W, (size_t)k * 256 + tid, f32), acc);
        }
        acc = fminf(fmaxf(acc, -1e6f), 1e6f);
        float x = (acc - ld_f(p.bn_mean, tid, f32))
                  * rsqrtf(fmaxf(ld_f(p.bn_var, tid, f32), 0.0f) + 1e-3f)
                  * ld_f(p.bn_gamma, tid, f32) + ld_f(p.bn_beta, tid, f32);
        float al = ld_f(p.alpha, tid, f32);
        hact[tid] = (x > 0.f) ? x : al * x;
        __syncthreads();
        if (tid < 7) {
            float s = ld_f(p.d1b, tid, f32);
            #pragma unroll 8
            for (int k = 0; k < 256; ++k)
                s = fmaf(hact[k], ld_f(p.d1W, k * 7 + tid, f32), s);
            lgts[tid] = fminf(fmaxf(s, -1e6f), 1e6f);
        }
        __syncthreads();
        if (tid == 0) {
            float mx = lgts[0];
            for (int j = 1; j < 7; ++j) mx = fmaxf(mx, lgts[j]);
            float ex[7]; float sum = 0.f;
            for (int j = 0; j < 7; ++j) { ex[j] = __expf(lgts[j] - mx); sum += ex[j]; }
            float inv = 1.0f / sum;
            for (int j = 0; j < 7; ++j) p.out[b * 7 + j] = ex[j] * inv;
        }
    }
}

extern "C" void kernel_launch(void* const* d_in, const int* in_sizes, int n_in,
                              void* d_out, int out_size, void* d_ws, size_t ws_size,
                              hipStream_t stream) {
    (void)in_sizes; (void)n_in; (void)out_size;

    P p;
    p.ids = (const int*)d_in[0];
    p.emb = d_in[1];
    for (int l = 0; l < 3; ++l) {
        p.Wm[0][l] = d_in[2 + l * 3];
        p.Um[0][l] = d_in[3 + l * 3];
        p.bm[0][l] = d_in[4 + l * 3];
        p.Wm[1][l] = d_in[11 + l * 3];
        p.Um[1][l] = d_in[12 + l * 3];
        p.bm[1][l] = d_in[13 + l * 3];
    }
    p.d0W      = d_in[20];
    p.d0b      = d_in[21];
    p.bn_gamma = d_in[22];
    p.bn_beta  = d_in[23];
    p.bn_mean  = d_in[24];
    p.bn_var   = d_in[25];
    p.alpha    = d_in[26];
    p.d1W      = d_in[27];
    p.d1b      = d_in[28];

    char* base = (ws_size >= NEED_WS || g_pool == nullptr) ? (char*)d_ws : (char*)g_pool;
    const size_t OFF_X  = 8192;                                        // flags@0 (3KB), epoch@4096
    const size_t OFF_H  = OFF_X + (size_t)TT * BB * EMBP * 2;          // +10,485,760
    const size_t OFF_HF = OFF_H + (size_t)3 * 2 * TT * BB * UU * 2;    // +100,663,296
    p.flags = (unsigned int*)base;
    p.epoch = (unsigned int*)(base + 4096);
    p.X     = (unsigned short*)(base + OFF_X);
    p.H     = (unsigned short*)(base + OFF_H);
    p.hf    = (float*)(base + OFF_HF);
    p.out   = (float*)d_out;

    hipMemsetAsync(base, 0, 8192, stream);   // flags+epoch; rest write-before-read
    hipLaunchKernelGGL(bilstm_persistent, dim3(NBLK), dim3(NTHR), 0, stream, p);
}

// Round 2
// 1867.195 us; speedup vs baseline: 2.4555x; 1.8069x over previous
//
#include <hip/hip_runtime.h>
#include <hip/hip_bf16.h>
#include <math.h>

// ---------------- problem constants ----------------
#define TT   128      // timesteps
#define BB   128      // batch
#define UU   512      // LSTM units
#define EMBD 300      // embedding dim
#define EMBP 320      // padded embedding dim (multiple of 32 for MFMA K)
#define NBLK 192      // 2 dir x 3 layers x 32 column-blocks (1 block/CU, 16 h-cols each)
#define DBLK 96       // blocks per direction
#define NTHR 256
#define BSTR 1056     // Bt row stride in elements (== 32 mod 64 -> conflict-free b128 reads)

using bf16x8 = __attribute__((ext_vector_type(8))) short;
using f32x4  = __attribute__((ext_vector_type(4))) float;

// ws layout: flags 768B | epoch @4096 | X 10MB | H 6 slots (write-once!) | hf
#define NEED_WS 111681536ull
static void* g_pool = nullptr;
__attribute__((constructor)) static void alloc_pool() {
    if (hipMalloc(&g_pool, 120ull * 1024ull * 1024ull) != hipSuccess) g_pool = nullptr;
}

__device__ __forceinline__ float b2f(unsigned short u) {
    union { unsigned int i; float f; } v; v.i = ((unsigned int)u) << 16; return v.f;
}
__device__ __forceinline__ unsigned short f2b(float f) {
    union { unsigned int i; float f; } v; v.f = f;
    unsigned int i = v.i;
    return (unsigned short)((i + 0x7fffu + ((i >> 16) & 1u)) >> 16);  // RNE
}
__device__ __forceinline__ unsigned short ld_bf(const void* p, size_t i, int f32) {
    return f32 ? f2b(((const float*)p)[i]) : ((const unsigned short*)p)[i];
}
__device__ __forceinline__ float ld_f(const void* p, size_t i, int f32) {
    return f32 ? ((const float*)p)[i] : b2f(((const unsigned short*)p)[i]);
}
__device__ __forceinline__ float clampz(float x) {
    return fminf(fmaxf(x, -60.0f), 60.0f);
}
__device__ __forceinline__ float sigm(float x)  { return 1.0f / (1.0f + __expf(-x)); }
__device__ __forceinline__ float ssign(float x) { return x / (1.0f + fabsf(x)); }

__device__ __forceinline__ int detect_f32(const void* emb) {
    const unsigned int* w = (const unsigned int*)emb;
    int cnt = 0;
    #pragma unroll
    for (int i = 0; i < 64; ++i) {
        unsigned int e = (w[i] >> 23) & 0xFFu;
        cnt += (e >= 96u && e <= 159u) ? 1 : 0;
    }
    return cnt >= 48;
}

struct P {
    const int* ids;
    const void* emb;
    const void* Wm[2][3];
    const void* Um[2][3];
    const void* bm[2][3];
    const void *d0W, *d0b;
    const void *bn_gamma, *bn_beta, *bn_mean, *bn_var;
    const void *alpha, *d1W, *d1b;
    unsigned short* X;      // [TT][BB][EMBP] bf16 (written once, fence-full barrier after)
    unsigned short* H;      // [3 slots][2 dirs][TT][BB][UU] bf16 — WRITE-ONCE, write-through
    float* hf;              // [2][BB][UU] fp32 — write-through
    unsigned int* flags;    // [NBLK] per-block generation flags
    unsigned int* epoch;    // epoch[0]=dir0, epoch[64]=dir1 (separate lines)
    float* out;             // [BB][7] fp32
};

#define EPOFF 64   // dir1 epoch word offset (256 B from dir0)

__device__ __forceinline__ unsigned int ald(const unsigned int* a) {
    return __hip_atomic_load(a, __ATOMIC_RELAXED, __HIP_MEMORY_SCOPE_AGENT);
}
__device__ __forceinline__ void ast(unsigned int* a, unsigned int v) {
    __hip_atomic_store(a, v, __ATOMIC_RELAXED, __HIP_MEMORY_SCOPE_AGENT);
}

// fence-FULL flat barrier (phase 0 only; X uses normal cached stores)
__device__ __forceinline__ void gsync_fence(unsigned int* flags, unsigned int gen) {
    __syncthreads();
    if (threadIdx.x == 0) {
        __threadfence();
        ast(&flags[blockIdx.x], gen);
    }
    if (threadIdx.x < 64) {
        const int i = threadIdx.x;
        for (;;) {
            bool ok = true;
            #pragma unroll
            for (int j = 0; j < NBLK / 64; ++j)
                ok = ok && (ald(&flags[i + j * 64]) >= gen);
            if (__all(ok)) break;
            __builtin_amdgcn_s_sleep(1);
        }
        __threadfence();
    }
    __syncthreads();
}

// Two-level aggregated per-direction barrier (fence-free; data is
// write-through + write-once). Leaves store own flag; the direction's
// aggregator block polls its 96 flags and publishes one epoch word;
// everyone polls that single word (same-address broadcast load).
__device__ __forceinline__ void gsync_dir(P& p, int dirbase, int eidx, int isagg, unsigned int gen) {
    __syncthreads();
    if (threadIdx.x == 0)
        ast(&p.flags[blockIdx.x], gen);
    if (isagg && threadIdx.x < 64) {
        const unsigned int* f = p.flags + dirbase + threadIdx.x;
        const bool two = (threadIdx.x < DBLK - 64);
        for (;;) {
            bool ok = (ald(f) >= gen) && (!two || (ald(f + 64) >= gen));
            if (__all(ok)) break;
            __builtin_amdgcn_s_sleep(1);
        }
        if (threadIdx.x == 0)
            ast(&p.epoch[eidx], gen);
    }
    if (threadIdx.x < 64) {
        const unsigned int* e = &p.epoch[eidx];
        while (ald(e) < gen) __builtin_amdgcn_s_sleep(1);
    }
    __syncthreads();
}

// full-grid aggregated barrier (before head)
__device__ __forceinline__ void gsync_all(P& p, int dirbase, int eidx, int isagg, unsigned int gen) {
    __syncthreads();
    if (threadIdx.x == 0)
        ast(&p.flags[blockIdx.x], gen);
    if (isagg && threadIdx.x < 64) {
        const unsigned int* f = p.flags + dirbase + threadIdx.x;
        const bool two = (threadIdx.x < DBLK - 64);
        for (;;) {
            bool ok = (ald(f) >= gen) && (!two || (ald(f + 64) >= gen));
            if (__all(ok)) break;
            __builtin_amdgcn_s_sleep(1);
        }
        if (threadIdx.x == 0)
            ast(&p.epoch[eidx], gen);
    }
    if (threadIdx.x < 64) {
        while (!((ald(&p.epoch[0]) >= gen) && (ald(&p.epoch[EPOFF]) >= gen)))
            __builtin_amdgcn_s_sleep(1);
    }
    __syncthreads();
}

// one K-segment of z += A @ B for this wave's two 16-row tiles x 4 col-tiles.
// A-fragment loaded once per K-tile, reused across the 4 col-tiles (1:4 load:MFMA).
// K1T compile-time so loops unroll; BOFF = column offset into Bt rows.
template<int K1T, int BOFF>
__device__ __forceinline__ void mfma_part(
    const unsigned short* __restrict__ a0p,    // A row r0, + ko
    const unsigned short* __restrict__ a1p,    // A row r1, + ko
    const unsigned short* __restrict__ bp,     // &Bt[l15][ko]
    f32x4 (&acc)[4][2])
{
    #pragma unroll 4
    for (int kt = 0; kt < K1T; kt += 32) {
        bf16x8 av0 = *(const bf16x8*)(a0p + kt);
        bf16x8 av1 = *(const bf16x8*)(a1p + kt);
        #pragma unroll
        for (int ct = 0; ct < 4; ++ct) {
            bf16x8 bv = *(const bf16x8*)(bp + (size_t)ct * 16 * BSTR + BOFF + kt);
            acc[ct][0] = __builtin_amdgcn_mfma_f32_16x16x32_bf16(av0, bv, acc[ct][0], 0, 0, 0);
            acc[ct][1] = __builtin_amdgcn_mfma_f32_16x16x32_bf16(av1, bv, acc[ct][1], 0, 0, 0);
        }
    }
}

__global__ __launch_bounds__(NTHR, 1) void bilstm_persistent(P p) {
    const int blk = blockIdx.x;
    const int tid = threadIdx.x;

    const int f32 = detect_f32(p.emb);
    unsigned int gen = 0;

    __shared__ __align__(16) unsigned short Bt[64][BSTR];  // B panel [n][k] (132 KB)
    __shared__ __align__(16) float zbuf[4][32][17];        // wave-private z transpose (8.5 KB)
    __shared__ float hact[256];
    __shared__ float lgts[8];

    // ---------------- phase 0: embedding gather (normal stores) ----------------
    for (int row = blk; row < TT * BB; row += NBLK) {
        int t = row >> 7, b = row & 127;
        int id = p.ids[b * TT + t];
        unsigned short* xr = p.X + (size_t)row * EMBP;
        for (int k2 = tid; k2 < EMBP; k2 += NTHR)
            xr[k2] = (k2 < EMBD) ? ld_bf(p.emb, (size_t)id * EMBD + k2, f32)
                                 : (unsigned short)0;
    }
    gsync_fence(p.flags, ++gen);             // only fence-full barrier in the kernel

    // block responsibilities: dir, layer (wavefront-pipelined), 16 h-cols, M=128
    const int dir     = (blk >= DBLK) ? 1 : 0;
    const int rb      = blk - dir * DBLK;
    const int layer   = rb >> 5;             // 0,1,2
    const int dirbase = dir * DBLK;
    const int eidx    = dir * EPOFF;
    const int isagg   = (rb == 0);
    const int j0      = (rb & 31) * 16;      // 16 h-cols per block

    const int wv   = tid >> 6;               // wave 0..3
    const int lane = tid & 63;
    const int l15  = lane & 15;
    const int quad = lane >> 4;

    const int rr   = lane & 31;              // gate thread: wave-local row
    const int jA   = (lane >> 5) * 2;        // 2 adjacent local h-cols per ct

    const int r0   = wv * 32 + l15;
    const int r1   = r0 + 16;
    const int ko   = quad * 8;

    float cS[4][2];                          // cell state per col-tile (registers)
    #pragma unroll
    for (int ct = 0; ct < 4; ++ct) { cS[ct][0] = 0.0f; cS[ct][1] = 0.0f; }

    const size_t seq = (size_t)TT * BB * UU;

    // ---- stage this block's B panel (64 gate-columns, its layer) into LDS — ONCE ----
    const int KW   = (layer == 0) ? EMBD : UU;
    const int K1   = (layer == 0) ? EMBP : UU;
    const int Ktot = K1 + UU;
    const void* Wmat = p.Wm[dir][layer];
    const void* Umat = p.Um[dir][layer];
    const void* bias = p.bm[dir][layer];
    {
        int n = tid >> 2, ks = tid & 3;                          // 4 threads per gate-col row
        int wcol = ((n >> 2) & 3) * UU + j0 + (n >> 4) * 4 + (n & 3);  // gate*512 + j0 + ct*4 + jj
        for (int k2 = ks; k2 < Ktot; k2 += 4) {
            unsigned short v;
            if (k2 < KW)      v = ld_bf(Wmat, (size_t)k2 * 2048 + wcol, f32);
            else if (k2 < K1) v = 0;
            else              v = ld_bf(Umat, (size_t)(k2 - K1) * 2048 + wcol, f32);
            Bt[n][k2] = v;
        }
    }
    float bz[4][4][2];
    #pragma unroll
    for (int ct = 0; ct < 4; ++ct)
        #pragma unroll
        for (int g = 0; g < 4; ++g) {
            bz[ct][g][0] = ld_f(bias, g * UU + j0 + ct * 4 + jA,     f32);
            bz[ct][g][1] = ld_f(bias, g * UU + j0 + ct * 4 + jA + 1, f32);
        }
    __syncthreads();

    // write-once slots: layer l writes slot l, reads slot l-1
    unsigned short*       Hl  = p.H + (size_t)(layer * 2 + dir) * seq;
    const unsigned short* Hin = (layer > 0) ? (p.H + (size_t)((layer - 1) * 2 + dir) * seq) : nullptr;

    const unsigned short* bp = &Bt[l15][ko];
    float* zb = &zbuf[wv][0][0];

    // ---------------- wavefront-pipelined step loop: 130 barriers/dir ----------------
    for (int s = 0; s < TT + 2; ++s) {
        const int t = s - layer;             // this layer's timestep at wavefront step s
        if (t >= 0 && t < TT) {
            const unsigned short* A2 = (t > 0) ? (Hl + (size_t)(t - 1) * BB * UU) : nullptr;

            f32x4 acc[4][2];
            #pragma unroll
            for (int ct = 0; ct < 4; ++ct) {
                acc[ct][0] = f32x4{0.f, 0.f, 0.f, 0.f};
                acc[ct][1] = f32x4{0.f, 0.f, 0.f, 0.f};
            }

            if (layer == 0) {
                int tx = dir ? (TT - 1 - t) : t;
                const unsigned short* A1 = p.X + (size_t)tx * BB * EMBP;
                mfma_part<EMBP, 0>(A1 + (size_t)r0 * EMBP + ko, A1 + (size_t)r1 * EMBP + ko, bp, acc);
                if (A2)
                    mfma_part<UU, EMBP>(A2 + (size_t)r0 * UU + ko, A2 + (size_t)r1 * UU + ko, bp, acc);
            } else {
                const unsigned short* A1 = Hin + (size_t)t * BB * UU;
                mfma_part<UU, 0>(A1 + (size_t)r0 * UU + ko, A1 + (size_t)r1 * UU + ko, bp, acc);
                if (A2)
                    mfma_part<UU, UU>(A2 + (size_t)r0 * UU + ko, A2 + (size_t)r1 * UU + ko, bp, acc);
            }

            // ---- gates, wave-private LDS transpose per col-tile (NO __syncthreads) ----
            // D layout: col = lane&15, row = quad*4 + reg  (m89-verified)
            #pragma unroll
            for (int ct = 0; ct < 4; ++ct) {
                #pragma unroll
                for (int r = 0; r < 4; ++r) {
                    zb[(quad * 4 + r) * 17 + l15]        = acc[ct][0][r];
                    zb[(16 + quad * 4 + r) * 17 + l15]   = acc[ct][1][r];
                }
                // in-order DS pipe: wave-level write->read needs no barrier
                float ziA = clampz(zb[rr * 17 +  0 + jA] + bz[ct][0][0]);
                float zfA = clampz(zb[rr * 17 +  4 + jA] + bz[ct][1][0]);
                float zgA = clampz(zb[rr * 17 +  8 + jA] + bz[ct][2][0]);
                float zoA = clampz(zb[rr * 17 + 12 + jA] + bz[ct][3][0]);
                float ziB = clampz(zb[rr * 17 +  1 + jA] + bz[ct][0][1]);
                float zfB = clampz(zb[rr * 17 +  5 + jA] + bz[ct][1][1]);
                float zgB = clampz(zb[rr * 17 +  9 + jA] + bz[ct][2][1]);
                float zoB = clampz(zb[rr * 17 + 13 + jA] + bz[ct][3][1]);
                float cpA = (t == 0) ? 0.0f : cS[ct][0];
                float cpB = (t == 0) ? 0.0f : cS[ct][1];
                float cnA = sigm(zfA) * cpA + sigm(ziA) * ssign(zgA);
                float cnB = sigm(zfB) * cpB + sigm(ziB) * ssign(zgB);
                cS[ct][0] = cnA; cS[ct][1] = cnB;
                float hA = sigm(zoA) * ssign(cnA);
                float hB = sigm(zoB) * ssign(cnB);
                // packed write-through store (device-coherent; never dirty in L2)
                const int R = wv * 32 + rr;
                const int col = j0 + ct * 4 + jA;
                unsigned int pk = (unsigned int)f2b(hA) | ((unsigned int)f2b(hB) << 16);
                __hip_atomic_store((unsigned int*)&Hl[(size_t)t * BB * UU + (size_t)R * UU + col],
                                   pk, __ATOMIC_RELAXED, __HIP_MEMORY_SCOPE_AGENT);
                if (layer == 2 && t == TT - 1) {
                    size_t o = (size_t)dir * BB * UU + (size_t)R * UU + col;
                    __hip_atomic_store(&p.hf[o],     hA, __ATOMIC_RELAXED, __HIP_MEMORY_SCOPE_AGENT);
                    __hip_atomic_store(&p.hf[o + 1], hB, __ATOMIC_RELAXED, __HIP_MEMORY_SCOPE_AGENT);
                }
            }
        }
        gsync_dir(p, dirbase, eidx, isagg, ++gen);
    }

    gsync_all(p, dirbase, eidx, isagg, ++gen);   // both dirs' hf complete before head

    // ---------------- head: block b handles batch row b (all fp32) ----------------
    if (blk < BB) {
        const int b = blk;
        const float* h0 = p.hf + (size_t)b * UU;
        const float* h1 = p.hf + (size_t)BB * UU + (size_t)b * UU;
        float acc = ld_f(p.d0b, tid, f32);
        #pragma unroll 8
        for (int k = 0; k < UU; ++k) {
            float a = 0.5f * (h0[k] + h1[k]);
            acc = fmaf(a, ld_f(p.d0W, (size_t)k * 256 + tid, f32), acc);
        }
        acc = fminf(fmaxf(acc, -1e6f), 1e6f);
        float x = (acc - ld_f(p.bn_mean, tid, f32))
                  * rsqrtf(fmaxf(ld_f(p.bn_var, tid, f32), 0.0f) + 1e-3f)
                  * ld_f(p.bn_gamma, tid, f32) + ld_f(p.bn_beta, tid, f32);
        float al = ld_f(p.alpha, tid, f32);
        hact[tid] = (x > 0.f) ? x : al * x;
        __syncthreads();
        if (tid < 7) {
            float s = ld_f(p.d1b, tid, f32);
            #pragma unroll 8
            for (int k = 0; k < 256; ++k)
                s = fmaf(hact[k], ld_f(p.d1W, k * 7 + tid, f32), s);
            lgts[tid] = fminf(fmaxf(s, -1e6f), 1e6f);
        }
        __syncthreads();
        if (tid == 0) {
            float mx = lgts[0];
            for (int j = 1; j < 7; ++j) mx = fmaxf(mx, lgts[j]);
            float ex[7]; float sum = 0.f;
            for (int j = 0; j < 7; ++j) { ex[j] = __expf(lgts[j] - mx); sum += ex[j]; }
            float inv = 1.0f / sum;
            for (int j = 0; j < 7; ++j) p.out[b * 7 + j] = ex[j] * inv;
        }
    }
}

extern "C" void kernel_launch(void* const* d_in, const int* in_sizes, int n_in,
                              void* d_out, int out_size, void* d_ws, size_t ws_size,
                              hipStream_t stream) {
    (void)in_sizes; (void)n_in; (void)out_size;

    P p;
    p.ids = (const int*)d_in[0];
    p.emb = d_in[1];
    for (int l = 0; l < 3; ++l) {
        p.Wm[0][l] = d_in[2 + l * 3];
        p.Um[0][l] = d_in[3 + l * 3];
        p.bm[0][l] = d_in[4 + l * 3];
        p.Wm[1][l] = d_in[11 + l * 3];
        p.Um[1][l] = d_in[12 + l * 3];
        p.bm[1][l] = d_in[13 + l * 3];
    }
    p.d0W      = d_in[20];
    p.d0b      = d_in[21];
    p.bn_gamma = d_in[22];
    p.bn_beta  = d_in[23];
    p.bn_mean  = d_in[24];
    p.bn_var   = d_in[25];
    p.alpha    = d_in[26];
    p.d1W      = d_in[27];
    p.d1b      = d_in[28];

    char* base = (ws_size >= NEED_WS || g_pool == nullptr) ? (char*)d_ws : (char*)g_pool;
    const size_t OFF_X  = 8192;                                        // flags@0, epoch@4096
    const size_t OFF_H  = OFF_X + (size_t)TT * BB * EMBP * 2;          // +10,485,760
    const size_t OFF_HF = OFF_H + (size_t)3 * 2 * TT * BB * UU * 2;    // +100,663,296
    p.flags = (unsigned int*)base;
    p.epoch = (unsigned int*)(base + 4096);
    p.X     = (unsigned short*)(base + OFF_X);
    p.H     = (unsigned short*)(base + OFF_H);
    p.hf    = (float*)(base + OFF_HF);
    p.out   = (float*)d_out;

    hipMemsetAsync(base, 0, 8192, stream);   // flags+epoch; rest write-before-read
    hipLaunchKernelGGL(bilstm_persistent, dim3(NBLK), dim3(NTHR), 0, stream, p);
}

// Round 3
// 1673.559 us; speedup vs baseline: 2.7396x; 1.1157x over previous
//
#include <hip/hip_runtime.h>
#include <hip/hip_bf16.h>
#include <math.h>

// ---------------- problem constants ----------------
#define TT   128      // timesteps
#define BB   128      // batch
#define UU   512      // LSTM units
#define EMBD 300      // embedding dim
#define EMBP 320      // padded embedding dim (multiple of 32 for MFMA K)
#define NBLK 192      // 2 dir x 3 layers x 32 column-blocks (1 block/CU, 16 h-cols each)
#define DBLK 96       // blocks per direction
#define NTHR 512      // 8 waves: one 16-row tile each -> 2 waves/SIMD
#define BSTR 1032     // Bt row stride el (2064 B = 16 mod 128 -> 4-bank shift/row, conflict-free b128)

using bf16x8 = __attribute__((ext_vector_type(8))) short;
using f32x4  = __attribute__((ext_vector_type(4))) float;

// ws layout: flags 768B | epoch @4096 | X 10MB | H 6 slots (write-once!) | hf
#define NEED_WS 111681536ull
static void* g_pool = nullptr;
__attribute__((constructor)) static void alloc_pool() {
    if (hipMalloc(&g_pool, 120ull * 1024ull * 1024ull) != hipSuccess) g_pool = nullptr;
}

__device__ __forceinline__ float b2f(unsigned short u) {
    union { unsigned int i; float f; } v; v.i = ((unsigned int)u) << 16; return v.f;
}
__device__ __forceinline__ unsigned short f2b(float f) {
    union { unsigned int i; float f; } v; v.f = f;
    unsigned int i = v.i;
    return (unsigned short)((i + 0x7fffu + ((i >> 16) & 1u)) >> 16);  // RNE
}
__device__ __forceinline__ unsigned short ld_bf(const void* p, size_t i, int f32) {
    return f32 ? f2b(((const float*)p)[i]) : ((const unsigned short*)p)[i];
}
__device__ __forceinline__ float ld_f(const void* p, size_t i, int f32) {
    return f32 ? ((const float*)p)[i] : b2f(((const unsigned short*)p)[i]);
}
__device__ __forceinline__ float clampz(float x) {
    return fminf(fmaxf(x, -60.0f), 60.0f);
}
__device__ __forceinline__ float sigm(float x)  { return 1.0f / (1.0f + __expf(-x)); }
__device__ __forceinline__ float ssign(float x) { return x / (1.0f + fabsf(x)); }

__device__ __forceinline__ int detect_f32(const void* emb) {
    const unsigned int* w = (const unsigned int*)emb;
    int cnt = 0;
    #pragma unroll
    for (int i = 0; i < 64; ++i) {
        unsigned int e = (w[i] >> 23) & 0xFFu;
        cnt += (e >= 96u && e <= 159u) ? 1 : 0;
    }
    return cnt >= 48;
}

struct P {
    const int* ids;
    const void* emb;
    const void* Wm[2][3];
    const void* Um[2][3];
    const void* bm[2][3];
    const void *d0W, *d0b;
    const void *bn_gamma, *bn_beta, *bn_mean, *bn_var;
    const void *alpha, *d1W, *d1b;
    unsigned short* X;      // [TT][BB][EMBP] bf16 (written once, fence-full barrier after)
    unsigned short* H;      // [3 slots][2 dirs][TT][BB][UU] bf16 — WRITE-ONCE, write-through
    float* hf;              // [2][BB][UU] fp32 — write-through
    unsigned int* flags;    // [NBLK] per-block generation flags
    unsigned int* epoch;    // epoch[0]=dir0, epoch[64]=dir1 (separate lines)
    float* out;             // [BB][7] fp32
};

#define EPOFF 64   // dir1 epoch word offset (256 B from dir0)

__device__ __forceinline__ unsigned int ald(const unsigned int* a) {
    return __hip_atomic_load(a, __ATOMIC_RELAXED, __HIP_MEMORY_SCOPE_AGENT);
}
__device__ __forceinline__ void ast(unsigned int* a, unsigned int v) {
    __hip_atomic_store(a, v, __ATOMIC_RELAXED, __HIP_MEMORY_SCOPE_AGENT);
}

// fence-FULL flat barrier (phase 0 only; X uses normal cached stores)
__device__ __forceinline__ void gsync_fence(unsigned int* flags, unsigned int gen) {
    __syncthreads();
    if (threadIdx.x == 0) {
        __threadfence();
        ast(&flags[blockIdx.x], gen);
    }
    if (threadIdx.x < 64) {
        const int i = threadIdx.x;
        for (;;) {
            bool ok = true;
            #pragma unroll
            for (int j = 0; j < NBLK / 64; ++j)
                ok = ok && (ald(&flags[i + j * 64]) >= gen);
            if (__all(ok)) break;
            __builtin_amdgcn_s_sleep(1);
        }
        __threadfence();
    }
    __syncthreads();
}

// Two-level aggregated per-direction barrier (fence-free; data is
// write-through + write-once). Leaves store own flag; the direction's
// aggregator block polls its 96 flags and publishes one epoch word;
// everyone polls that single word (same-address broadcast load).
__device__ __forceinline__ void gsync_dir(P& p, int dirbase, int eidx, int isagg, unsigned int gen) {
    __syncthreads();
    if (threadIdx.x == 0)
        ast(&p.flags[blockIdx.x], gen);
    if (isagg && threadIdx.x < 64) {
        const unsigned int* f = p.flags + dirbase + threadIdx.x;
        const bool two = (threadIdx.x < DBLK - 64);
        for (;;) {
            bool ok = (ald(f) >= gen) && (!two || (ald(f + 64) >= gen));
            if (__all(ok)) break;
            __builtin_amdgcn_s_sleep(1);
        }
        if (threadIdx.x == 0)
            ast(&p.epoch[eidx], gen);
    }
    if (threadIdx.x < 64) {
        const unsigned int* e = &p.epoch[eidx];
        while (ald(e) < gen) __builtin_amdgcn_s_sleep(1);
    }
    __syncthreads();
}

// full-grid aggregated barrier (before head)
__device__ __forceinline__ void gsync_all(P& p, int dirbase, int eidx, int isagg, unsigned int gen) {
    __syncthreads();
    if (threadIdx.x == 0)
        ast(&p.flags[blockIdx.x], gen);
    if (isagg && threadIdx.x < 64) {
        const unsigned int* f = p.flags + dirbase + threadIdx.x;
        const bool two = (threadIdx.x < DBLK - 64);
        for (;;) {
            bool ok = (ald(f) >= gen) && (!two || (ald(f + 64) >= gen));
            if (__all(ok)) break;
            __builtin_amdgcn_s_sleep(1);
        }
        if (threadIdx.x == 0)
            ast(&p.epoch[eidx], gen);
    }
    if (threadIdx.x < 64) {
        while (!((ald(&p.epoch[0]) >= gen) && (ald(&p.epoch[EPOFF]) >= gen)))
            __builtin_amdgcn_s_sleep(1);
    }
    __syncthreads();
}

// one K-segment of z += A @ B for this wave's 16-row tile x 4 col-tiles.
// A-fragment loaded once per K-tile, reused across the 4 col-tiles (1:4 load:MFMA).
// K1T compile-time so loops unroll; BOFF = column offset into Bt rows.
template<int K1T, int BOFF>
__device__ __forceinline__ void mfma_part(
    const unsigned short* __restrict__ a0p,    // A row r0, + ko
    const unsigned short* __restrict__ bp,     // &Bt[l15][ko]
    f32x4 (&acc)[4])
{
    #pragma unroll 4
    for (int kt = 0; kt < K1T; kt += 32) {
        bf16x8 av = *(const bf16x8*)(a0p + kt);
        #pragma unroll
        for (int ct = 0; ct < 4; ++ct) {
            bf16x8 bv = *(const bf16x8*)(bp + (size_t)ct * 16 * BSTR + BOFF + kt);
            acc[ct] = __builtin_amdgcn_mfma_f32_16x16x32_bf16(av, bv, acc[ct], 0, 0, 0);
        }
    }
}

__global__ __launch_bounds__(NTHR, 1) void bilstm_persistent(P p) {
    const int blk = blockIdx.x;
    const int tid = threadIdx.x;

    const int f32 = detect_f32(p.emb);
    unsigned int gen = 0;

    __shared__ __align__(16) unsigned short Bt[64][BSTR];  // B panel [n][k] (129 KB)
    __shared__ __align__(16) float zbuf[8][2][16][17];     // per-wave 2-tile z transpose (17 KB)
    __shared__ float hact[256];
    __shared__ float lgts[8];

    // ---------------- phase 0: embedding gather (normal stores) ----------------
    for (int row = blk; row < TT * BB; row += NBLK) {
        int t = row >> 7, b = row & 127;
        int id = p.ids[b * TT + t];
        unsigned short* xr = p.X + (size_t)row * EMBP;
        for (int k2 = tid; k2 < EMBP; k2 += NTHR)
            xr[k2] = (k2 < EMBD) ? ld_bf(p.emb, (size_t)id * EMBD + k2, f32)
                                 : (unsigned short)0;
    }
    gsync_fence(p.flags, ++gen);             // only fence-full barrier in the kernel

    // block responsibilities: dir, layer (wavefront-pipelined), 16 h-cols, M=128
    const int dir     = (blk >= DBLK) ? 1 : 0;
    const int rb      = blk - dir * DBLK;
    const int layer   = rb >> 5;             // 0,1,2
    const int dirbase = dir * DBLK;
    const int eidx    = dir * EPOFF;
    const int isagg   = (rb == 0);
    const int j0      = (rb & 31) * 16;      // 16 h-cols per block

    const int wv   = tid >> 6;               // wave 0..7, one 16-row tile each
    const int lane = tid & 63;
    const int l15  = lane & 15;
    const int quad = lane >> 4;

    // gate-phase mapping: row16 = lane&15, jp = (lane>>4)&1 (col pair), ch = lane>>5 (ct half)
    const int row16 = lane & 15;
    const int jp    = (lane >> 4) & 1;
    const int ch    = lane >> 5;

    const int r0   = wv * 16 + l15;
    const int ko   = quad * 8;

    float cS[2][2];                          // cell state: [pp][colA/colB]
    cS[0][0] = cS[0][1] = cS[1][0] = cS[1][1] = 0.0f;

    const size_t seq = (size_t)TT * BB * UU;

    // ---- stage this block's B panel (64 gate-columns, its layer) into LDS — ONCE ----
    const int KW   = (layer == 0) ? EMBD : UU;
    const int K1   = (layer == 0) ? EMBP : UU;
    const int Ktot = K1 + UU;
    const void* Wmat = p.Wm[dir][layer];
    const void* Umat = p.Um[dir][layer];
    const void* bias = p.bm[dir][layer];
    {
        int n = tid >> 3, ks = tid & 7;                          // 8 threads per gate-col row
        int wcol = ((n >> 2) & 3) * UU + j0 + (n >> 4) * 4 + (n & 3);  // gate*512 + j0 + ct*4 + jj
        for (int k2 = ks; k2 < Ktot; k2 += 8) {
            unsigned short v;
            if (k2 < KW)      v = ld_bf(Wmat, (size_t)k2 * 2048 + wcol, f32);
            else if (k2 < K1) v = 0;
            else              v = ld_bf(Umat, (size_t)(k2 - K1) * 2048 + wcol, f32);
            Bt[n][k2] = v;
        }
    }
    // per-lane bias: pass pp handles ct = 2*pp + ch, cols 2*jp, 2*jp+1
    float bz[2][4][2];
    #pragma unroll
    for (int pp = 0; pp < 2; ++pp) {
        const int cb = j0 + (2 * pp + ch) * 4 + 2 * jp;
        #pragma unroll
        for (int g = 0; g < 4; ++g) {
            bz[pp][g][0] = ld_f(bias, g * UU + cb,     f32);
            bz[pp][g][1] = ld_f(bias, g * UU + cb + 1, f32);
        }
    }
    __syncthreads();

    // write-once slots: layer l writes slot l, reads slot l-1
    unsigned short*       Hl  = p.H + (size_t)(layer * 2 + dir) * seq;
    const unsigned short* Hin = (layer > 0) ? (p.H + (size_t)((layer - 1) * 2 + dir) * seq) : nullptr;

    const unsigned short* bp = &Bt[l15][ko];
    float* zbw = &zbuf[wv][0][0][0];         // this wave's private 2x16x17 buffer

    // ---------------- wavefront-pipelined step loop: 130 barriers/dir ----------------
    for (int s = 0; s < TT + 2; ++s) {
        const int t = s - layer;             // this layer's timestep at wavefront step s
        if (t >= 0 && t < TT) {
            const unsigned short* A2 = (t > 0) ? (Hl + (size_t)(t - 1) * BB * UU) : nullptr;

            f32x4 acc[4];
            #pragma unroll
            for (int ct = 0; ct < 4; ++ct) acc[ct] = f32x4{0.f, 0.f, 0.f, 0.f};

            if (layer == 0) {
                int tx = dir ? (TT - 1 - t) : t;
                const unsigned short* A1 = p.X + (size_t)tx * BB * EMBP;
                mfma_part<EMBP, 0>(A1 + (size_t)r0 * EMBP + ko, bp, acc);
                if (A2)
                    mfma_part<UU, EMBP>(A2 + (size_t)r0 * UU + ko, bp, acc);
            } else {
                const unsigned short* A1 = Hin + (size_t)t * BB * UU;
                mfma_part<UU, 0>(A1 + (size_t)r0 * UU + ko, bp, acc);
                if (A2)
                    mfma_part<UU, UU>(A2 + (size_t)r0 * UU + ko, bp, acc);
            }

            // ---- gates, wave-private LDS transpose, 2 ct per pass (NO __syncthreads) ----
            // D layout: col = lane&15, row = quad*4 + reg  (m89-verified)
            #pragma unroll
            for (int pp = 0; pp < 2; ++pp) {
                #pragma unroll
                for (int cth = 0; cth < 2; ++cth) {
                    const int ct = pp * 2 + cth;
                    #pragma unroll
                    for (int r = 0; r < 4; ++r)
                        zbw[cth * 272 + (quad * 4 + r) * 17 + l15] = acc[ct][r];
                }
                // in-order DS pipe: wave-level write->read needs no barrier
                const int zb0 = ch * 272 + row16 * 17 + 2 * jp;
                float ziA = clampz(zbw[zb0 +  0] + bz[pp][0][0]);
                float zfA = clampz(zbw[zb0 +  4] + bz[pp][1][0]);
                float zgA = clampz(zbw[zb0 +  8] + bz[pp][2][0]);
                float zoA = clampz(zbw[zb0 + 12] + bz[pp][3][0]);
                float ziB = clampz(zbw[zb0 +  1] + bz[pp][0][1]);
                float zfB = clampz(zbw[zb0 +  5] + bz[pp][1][1]);
                float zgB = clampz(zbw[zb0 +  9] + bz[pp][2][1]);
                float zoB = clampz(zbw[zb0 + 13] + bz[pp][3][1]);
                float cpA = (t == 0) ? 0.0f : cS[pp][0];
                float cpB = (t == 0) ? 0.0f : cS[pp][1];
                float cnA = sigm(zfA) * cpA + sigm(ziA) * ssign(zgA);
                float cnB = sigm(zfB) * cpB + sigm(ziB) * ssign(zgB);
                cS[pp][0] = cnA; cS[pp][1] = cnB;
                float hA = sigm(zoA) * ssign(cnA);
                float hB = sigm(zoB) * ssign(cnB);
                // packed write-through store (device-coherent; never dirty in L2)
                const int R   = wv * 16 + row16;
                const int col = j0 + (2 * pp + ch) * 4 + 2 * jp;
                unsigned int pk = (unsigned int)f2b(hA) | ((unsigned int)f2b(hB) << 16);
                __hip_atomic_store((unsigned int*)&Hl[(size_t)t * BB * UU + (size_t)R * UU + col],
                                   pk, __ATOMIC_RELAXED, __HIP_MEMORY_SCOPE_AGENT);
                if (layer == 2 && t == TT - 1) {
                    size_t o = (size_t)dir * BB * UU + (size_t)R * UU + col;
                    __hip_atomic_store(&p.hf[o],     hA, __ATOMIC_RELAXED, __HIP_MEMORY_SCOPE_AGENT);
                    __hip_atomic_store(&p.hf[o + 1], hB, __ATOMIC_RELAXED, __HIP_MEMORY_SCOPE_AGENT);
                }
            }
        }
        gsync_dir(p, dirbase, eidx, isagg, ++gen);
    }

    gsync_all(p, dirbase, eidx, isagg, ++gen);   // both dirs' hf complete before head

    // ---------------- head: block b handles batch row b (all fp32) ----------------
    if (blk < BB) {
        const int b = blk;
        if (tid < 256) {
            const float* h0 = p.hf + (size_t)b * UU;
            const float* h1 = p.hf + (size_t)BB * UU + (size_t)b * UU;
            float acc = ld_f(p.d0b, tid, f32);
            #pragma unroll 8
            for (int k = 0; k < UU; ++k) {
                float a = 0.5f * (h0[k] + h1[k]);
                acc = fmaf(a, ld_f(p.d0W, (size_t)k * 256 + tid, f32), acc);
            }
            acc = fminf(fmaxf(acc, -1e6f), 1e6f);
            float x = (acc - ld_f(p.bn_mean, tid, f32))
                      * rsqrtf(fmaxf(ld_f(p.bn_var, tid, f32), 0.0f) + 1e-3f)
                      * ld_f(p.bn_gamma, tid, f32) + ld_f(p.bn_beta, tid, f32);
            float al = ld_f(p.alpha, tid, f32);
            hact[tid] = (x > 0.f) ? x : al * x;
        }
        __syncthreads();
        if (tid < 7) {
            float s = ld_f(p.d1b, tid, f32);
            #pragma unroll 8
            for (int k = 0; k < 256; ++k)
                s = fmaf(hact[k], ld_f(p.d1W, k * 7 + tid, f32), s);
            lgts[tid] = fminf(fmaxf(s, -1e6f), 1e6f);
        }
        __syncthreads();
        if (tid == 0) {
            float mx = lgts[0];
            for (int j = 1; j < 7; ++j) mx = fmaxf(mx, lgts[j]);
            float ex[7]; float sum = 0.f;
            for (int j = 0; j < 7; ++j) { ex[j] = __expf(lgts[j] - mx); sum += ex[j]; }
            float inv = 1.0f / sum;
            for (int j = 0; j < 7; ++j) p.out[b * 7 + j] = ex[j] * inv;
        }
    }
}

extern "C" void kernel_launch(void* const* d_in, const int* in_sizes, int n_in,
                              void* d_out, int out_size, void* d_ws, size_t ws_size,
                              hipStream_t stream) {
    (void)in_sizes; (void)n_in; (void)out_size;

    P p;
    p.ids = (const int*)d_in[0];
    p.emb = d_in[1];
    for (int l = 0; l < 3; ++l) {
        p.Wm[0][l] = d_in[2 + l * 3];
        p.Um[0][l] = d_in[3 + l * 3];
        p.bm[0][l] = d_in[4 + l * 3];
        p.Wm[1][l] = d_in[11 + l * 3];
        p.Um[1][l] = d_in[12 + l * 3];
        p.bm[1][l] = d_in[13 + l * 3];
    }
    p.d0W      = d_in[20];
    p.d0b      = d_in[21];
    p.bn_gamma = d_in[22];
    p.bn_beta  = d_in[23];
    p.bn_mean  = d_in[24];
    p.bn_var   = d_in[25];
    p.alpha    = d_in[26];
    p.d1W      = d_in[27];
    p.d1b      = d_in[28];

    char* base = (ws_size >= NEED_WS || g_pool == nullptr) ? (char*)d_ws : (char*)g_pool;
    const size_t OFF_X  = 8192;                                        // flags@0, epoch@4096
    const size_t OFF_H  = OFF_X + (size_t)TT * BB * EMBP * 2;          // +10,485,760
    const size_t OFF_HF = OFF_H + (size_t)3 * 2 * TT * BB * UU * 2;    // +100,663,296
    p.flags = (unsigned int*)base;
    p.epoch = (unsigned int*)(base + 4096);
    p.X     = (unsigned short*)(base + OFF_X);
    p.H     = (unsigned short*)(base + OFF_H);
    p.hf    = (float*)(base + OFF_HF);
    p.out   = (float*)d_out;

    hipMemsetAsync(base, 0, 8192, stream);   // flags+epoch; rest write-before-read
    hipLaunchKernelGGL(bilstm_persistent, dim3(NBLK), dim3(NTHR), 0, stream, p);
}